// Round 5
// baseline (257.265 us; speedup 1.0000x reference)
//
#include <hip/hip_runtime.h>
#include <hip/hip_bf16.h>
#include <math.h>

// Problem constants
#define BATCH   65536
#define FDIM    512
#define VDIM    28
#define TILE_R  64              // rows per block = 2 waves x 32-row M-frags
#define NKS     32              // x-GEMM k-steps of 16 (512/16)
#define W1N     (NKS * 4 * 64 * 8)   // 65536 packed bf16 per hi/lo array
#define W2N     (2 * 4 * 64 * 8)     // 4096  (h-GEMM: K=28 padded to 32 -> 2 k-steps)

// Weight packing: W' columns in 4 sections of stride 32 (n = sect*32 + v):
//   sect0 = gate-z cols, sect1 = gate-r, sect2 = gate-h, sect3 = Co (x) / Uo (h).
// Section stride 32 == MFMA N-tile width, so D-fragment col (lane&31) == vocab v.

using short8 = __attribute__((ext_vector_type(8))) short;   // 8 bf16
using f32x16 = __attribute__((ext_vector_type(16))) float;  // 32x32 acc frag

__device__ __forceinline__ float sigmoidf_(float x) { return 1.0f / (1.0f + __expf(-x)); }
__device__ __forceinline__ float tanhf_(float x) { return 1.0f - 2.0f / (1.0f + __expf(2.0f * x)); }

__device__ __forceinline__ unsigned short f2bf_rne(float f) {
    unsigned u = __float_as_uint(f);
    u += 0x7FFFu + ((u >> 16) & 1u);
    return (unsigned short)(u >> 16);
}

// split two f32 into packed hi-bf16 pair + lo-bf16 pair (truncation; residual ~exact)
__device__ __forceinline__ void split2(float f0, float f1, unsigned& hp, unsigned& lp) {
    unsigned u0 = __float_as_uint(f0), u1 = __float_as_uint(f1);
    hp = (u0 >> 16) | (u1 & 0xFFFF0000u);
    float d0 = f0 - __uint_as_float(u0 & 0xFFFF0000u);
    float d1 = f1 - __uint_as_float(u1 & 0xFFFF0000u);
    unsigned v0 = __float_as_uint(d0), v1 = __float_as_uint(d1);
    lp = (v0 >> 16) | (v1 & 0xFFFF0000u);
}

// ---- Prep: pack x-weights W1=[gk_z|gk_r|gk_h|Co] (512x128) and h-weights
//      W2=[rk_z|rk_r|rk_h|Uo] (32x128, k>=28 zero) into B-fragment order
//      [ks][nf][lane][j] as hi/lo bf16 pairs; build t[j]=emb[j]·Wo. ----
__global__ void prep_kernel(const float* __restrict__ gk, const float* __restrict__ co,
                            const float* __restrict__ rk, const float* __restrict__ uo,
                            const float* __restrict__ emb, const float* __restrict__ wo,
                            unsigned short* __restrict__ w1h, unsigned short* __restrict__ w1l,
                            unsigned short* __restrict__ w2h, unsigned short* __restrict__ w2l,
                            float* __restrict__ tt) {
    int tid = blockIdx.x * 256 + threadIdx.x;
    int nth = gridDim.x * 256;
    for (int idx = tid; idx < W1N; idx += nth) {
        int j = idx & 7, lane = (idx >> 3) & 63, nf = (idx >> 9) & 3, ks = idx >> 11;
        int k = ks * 16 + ((lane >> 5) << 3) + j;    // B row (K, 0..511)
        int v = lane & 31;                           // col within section
        float val = 0.0f;
        if (v < VDIM) val = (nf < 3) ? gk[k * 84 + nf * 28 + v] : co[k * VDIM + v];
        unsigned short hi = f2bf_rne(val);
        float fh = __uint_as_float(((unsigned)hi) << 16);
        w1h[idx] = hi;
        w1l[idx] = f2bf_rne(val - fh);
    }
    for (int idx = tid; idx < W2N; idx += nth) {
        int j = idx & 7, lane = (idx >> 3) & 63, nf = (idx >> 9) & 3, ks = idx >> 11;
        int k = ks * 16 + ((lane >> 5) << 3) + j;    // 0..31, valid < 28
        int v = lane & 31;
        float val = 0.0f;
        if (v < VDIM && k < VDIM) val = (nf < 3) ? rk[k * 84 + nf * 28 + v] : uo[k * VDIM + v];
        unsigned short hi = f2bf_rne(val);
        float fh = __uint_as_float(((unsigned)hi) << 16);
        w2h[idx] = hi;
        w2l[idx] = f2bf_rne(val - fh);
    }
    if (tid < VDIM) {
        float s = 0.0f;
        for (int e = 0; e < VDIM; e++) s = fmaf(emb[tid * VDIM + e], wo[e], s);
        tt[tid] = s;
    }
}

#define MFMA(A, B, C) __builtin_amdgcn_mfma_f32_32x32x16_bf16(A, B, C, 0, 0, 0)
#define SPLIT8(A0, A1, AH, AL)                                        \
    {                                                                 \
        uint4 hu_, lu_;                                               \
        split2(A0.x, A0.y, hu_.x, lu_.x);                             \
        split2(A0.z, A0.w, hu_.y, lu_.y);                             \
        split2(A1.x, A1.y, hu_.z, lu_.z);                             \
        split2(A1.z, A1.w, hu_.w, lu_.w);                             \
        AH = __builtin_bit_cast(short8, hu_);                         \
        AL = __builtin_bit_cast(short8, lu_);                         \
    }
// full split product: (ah+al)(bh+bl) — al*bl is free under the memory roofline
#define MFMA4(ACC, AH, AL, BH, BL)                                    \
    ACC = MFMA(AH, BH, ACC); ACC = MFMA(AL, BH, ACC);                 \
    ACC = MFMA(AH, BL, ACC); ACC = MFMA(AL, BL, ACC);

// ---- Main fused kernel: split-bf16 MFMA (x-GEMM + h-GEMM, shared accs for
//      z/r/logit sections) + in-register gates + shfl softmax ----
__global__ __launch_bounds__(128, 2) void gru_main_kernel(
    const float* __restrict__ x,    // [B,512]
    const int*   __restrict__ pp,   // [B,28]
    const float* __restrict__ ps,   // [B,28]
    const float* __restrict__ bias, // [2,84]
    const float* __restrict__ bo,   // [1,28]
    const unsigned short* __restrict__ w1h, const unsigned short* __restrict__ w1l,
    const unsigned short* __restrict__ w2h, const unsigned short* __restrict__ w2l,
    const float* __restrict__ tt,   // [28]
    float* __restrict__ out)        // [B*28 pred][B*28 gru_out]
{
    __shared__ float hbuf[TILE_R * VDIM];   // prev_state tile (fp32)
    __shared__ int   ppbuf[TILE_R * VDIM];  // prev_prediction tile
    __shared__ float tts[32];               // t[] table for the emb-gather trick

    const int t = threadIdx.x;
    const int wid = t >> 6, l = t & 63;
    const int cl = l & 31, gh = l >> 5;
    const long row0 = (long)blockIdx.x * TILE_R;
    const int m0 = 32 * wid;

    // coalesced stage of per-row small inputs (consumed after the one barrier)
    for (int i = t; i < TILE_R * VDIM; i += 128) {
        hbuf[i]  = ps[row0 * VDIM + i];
        ppbuf[i] = pp[row0 * VDIM + i];
    }
    if (t < 32) tts[t] = (t < VDIM) ? tt[t] : 0.0f;

    // per-lane column scalars (v = cl)
    const int vc = (cl < VDIM) ? cl : (VDIM - 1);
    const float b0z = bias[vc],      b0r = bias[28 + vc],  b0h = bias[56 + vc];
    const float b1z = bias[84 + vc], b1r = bias[112 + vc], b1h = bias[140 + vc];
    const float bov = bo[vc];

    // Shared accumulators: z, r, logit(c) take x-GEMM + h-GEMM contributions;
    // xh / hh must stay separate (hcand = tanh(xh + r*hh + biases)).
    f32x16 accz = {}, accr = {}, acch = {}, accc = {}, hacch = {};

    // ---- h-GEMM: h @ [rk | Uo], K=28 padded to 32 (2 k-steps) ----
    {
        const float* hrow = ps + (row0 + m0 + cl) * (long)VDIM;
        const short8* bh8 = (const short8*)w2h + l;
        const short8* bl8 = (const short8*)w2l + l;
        short8 ah, al, bh, bl;
        {   // k-step 0: k = gh*8 + j  (floats 0..15, all valid)
            float4 a0 = *(const float4*)(hrow + gh * 8);
            float4 a1 = *(const float4*)(hrow + gh * 8 + 4);
            SPLIT8(a0, a1, ah, al);
            bh = bh8[0];   bl = bl8[0];   MFMA4(accz,  ah, al, bh, bl);
            bh = bh8[64];  bl = bl8[64];  MFMA4(accr,  ah, al, bh, bl);
            bh = bh8[128]; bl = bl8[128]; MFMA4(hacch, ah, al, bh, bl);
            bh = bh8[192]; bl = bl8[192]; MFMA4(accc,  ah, al, bh, bl);
        }
        {   // k-step 1: k = 16 + gh*8 + j (floats 16..27 valid; 28..31 -> 0)
            float4 a0 = *(const float4*)(hrow + 16 + gh * 8);  // 16..19 | 24..27
            float4 a1 = make_float4(0.f, 0.f, 0.f, 0.f);
            if (!gh) a1 = *(const float4*)(hrow + 20);         // 20..23 (gh=1: zeros)
            SPLIT8(a0, a1, ah, al);
            bh = bh8[256]; bl = bl8[256]; MFMA4(accz,  ah, al, bh, bl);
            bh = bh8[320]; bl = bl8[320]; MFMA4(accr,  ah, al, bh, bl);
            bh = bh8[384]; bl = bl8[384]; MFMA4(hacch, ah, al, bh, bl);
            bh = bh8[448]; bl = bl8[448]; MFMA4(accc,  ah, al, bh, bl);
        }
    }

    // ---- x-GEMM: x @ [gk | Co], 32 k-steps, A direct from global (read once) ----
    {
        const float* xrow = x + (row0 + m0 + cl) * (long)FDIM + gh * 8;
        const short8* bh8 = (const short8*)w1h + l;
        const short8* bl8 = (const short8*)w1l + l;
        #pragma unroll 4
        for (int ks = 0; ks < NKS; ++ks) {
            float4 a0 = *(const float4*)(xrow + ks * 16);
            float4 a1 = *(const float4*)(xrow + ks * 16 + 4);
            short8 ah, al, bh, bl;
            SPLIT8(a0, a1, ah, al);
            const int kb = ks * 256;
            bh = bh8[kb];       bl = bl8[kb];       MFMA4(accz, ah, al, bh, bl);
            bh = bh8[kb + 64];  bl = bl8[kb + 64];  MFMA4(accr, ah, al, bh, bl);
            bh = bh8[kb + 128]; bl = bl8[kb + 128]; MFMA4(acch, ah, al, bh, bl);
            bh = bh8[kb + 192]; bl = bl8[kb + 192]; MFMA4(accc, ah, al, bh, bl);
        }
    }

    __syncthreads();   // hbuf/ppbuf/tts ready

    // ---- Register epilogue: lane owns (v=cl, rows rowf(r)); softmax via shfl ----
    #pragma unroll
    for (int r = 0; r < 16; ++r) {
        const int rowf = (r & 3) + ((r >> 2) << 3) + (gh << 2);  // D-frag row (m74/m101)
        const int grow = m0 + rowf;
        const long orow = row0 + grow;
        const float hp  = hbuf[grow * VDIM + vc];
        const int   ppv = ppbuf[grow * VDIM + vc];

        const float z  = sigmoidf_(accz[r] + b0z + b1z);
        const float rg = sigmoidf_(accr[r] + b0r + b1r);
        const float hc = tanhf_(acch[r] + b0h + rg * (hacch[r] + b1h));
        const float go = z * hp + (1.0f - z) * hc;
        const float logit = tts[ppv & 31] + accc[r] + bov;

        // softmax across v: reduce within the aligned 32-lane group
        float mx = (cl < VDIM) ? logit : -1e30f;
        mx = fmaxf(mx, __shfl_xor(mx, 16));
        mx = fmaxf(mx, __shfl_xor(mx, 8));
        mx = fmaxf(mx, __shfl_xor(mx, 4));
        mx = fmaxf(mx, __shfl_xor(mx, 2));
        mx = fmaxf(mx, __shfl_xor(mx, 1));
        float p = (cl < VDIM) ? __expf(logit - mx) : 0.0f;
        float s = p;
        s += __shfl_xor(s, 16);
        s += __shfl_xor(s, 8);
        s += __shfl_xor(s, 4);
        s += __shfl_xor(s, 2);
        s += __shfl_xor(s, 1);

        if (cl < VDIM) {
            out[orow * VDIM + cl] = p / s;                          // pred
            out[(long)BATCH * VDIM + orow * VDIM + cl] = go;        // gru_out
        }
    }
}

extern "C" void kernel_launch(void* const* d_in, const int* in_sizes, int n_in,
                              void* d_out, int out_size, void* d_ws, size_t ws_size,
                              hipStream_t stream) {
    const float* x    = (const float*)d_in[0];
    const int*   pp   = (const int*)  d_in[1];
    const float* ps   = (const float*)d_in[2];
    const float* gk   = (const float*)d_in[3];
    const float* rk   = (const float*)d_in[4];
    const float* bias = (const float*)d_in[5];
    const float* wo   = (const float*)d_in[6];
    const float* uo   = (const float*)d_in[7];
    const float* co   = (const float*)d_in[8];
    const float* bo   = (const float*)d_in[9];
    const float* emb  = (const float*)d_in[10];

    unsigned short* w1h = (unsigned short*)d_ws;   // 65536 ushort = 128 KB
    unsigned short* w1l = w1h + W1N;               // 128 KB
    unsigned short* w2h = w1l + W1N;               // 8 KB
    unsigned short* w2l = w2h + W2N;               // 8 KB
    float*          tt  = (float*)(w2l + W2N);     // 112 B   (total ws ~272.1 KB)

    prep_kernel<<<64, 256, 0, stream>>>(gk, co, rk, uo, emb, wo, w1h, w1l, w2h, w2l, tt);
    gru_main_kernel<<<BATCH / TILE_R, 128, 0, stream>>>(
        x, pp, ps, bias, bo, w1h, w1l, w2h, w2l, tt, (float*)d_out);
}

// Round 6
// 254.710 us; speedup vs baseline: 1.0100x; 1.0100x over previous
//
#include <hip/hip_runtime.h>
#include <hip/hip_bf16.h>
#include <math.h>

// Problem constants
#define BATCH   65536
#define FDIM    512
#define VDIM    28
#define TILE_R  64              // rows per block = 2 M-frags x 32 rows
#define W1N     (32 * 4 * 64 * 8)    // 65536 packed bf16 per hi/lo array (x-weights)
#define W2N     (2 * 4 * 64 * 8)     // 4096 (h-weights: K=28 padded to 32 -> 2 k-steps)

using short8 = __attribute__((ext_vector_type(8))) short;   // 8 bf16
using f32x16 = __attribute__((ext_vector_type(16))) float;  // 32x32 acc frag

__device__ __forceinline__ float sigmoidf_(float x) { return 1.0f / (1.0f + __expf(-x)); }
__device__ __forceinline__ float tanhf_(float x) { return 1.0f - 2.0f / (1.0f + __expf(2.0f * x)); }

__device__ __forceinline__ unsigned short f2bf_rne(float f) {
    unsigned u = __float_as_uint(f);
    u += 0x7FFFu + ((u >> 16) & 1u);
    return (unsigned short)(u >> 16);
}

__device__ __forceinline__ void split2(float f0, float f1, unsigned& hp, unsigned& lp) {
    unsigned u0 = __float_as_uint(f0), u1 = __float_as_uint(f1);
    hp = (u0 >> 16) | (u1 & 0xFFFF0000u);
    float d0 = f0 - __uint_as_float(u0 & 0xFFFF0000u);
    float d1 = f1 - __uint_as_float(u1 & 0xFFFF0000u);
    unsigned v0 = __float_as_uint(d0), v1 = __float_as_uint(d1);
    lp = (v0 >> 16) | (v1 & 0xFFFF0000u);
}

// ---- Prep: pack W1=[gk_z|gk_r|gk_h|Co] (512x128) and W2=[rk_z|rk_r|rk_h|Uo]
//      (32x128) into B-fragment order [ks][nf][lane][j] hi/lo; t[j]=emb[j]·Wo ----
__global__ void prep_kernel(const float* __restrict__ gk, const float* __restrict__ co,
                            const float* __restrict__ rk, const float* __restrict__ uo,
                            const float* __restrict__ emb, const float* __restrict__ wo,
                            unsigned short* __restrict__ w1h, unsigned short* __restrict__ w1l,
                            unsigned short* __restrict__ w2h, unsigned short* __restrict__ w2l,
                            float* __restrict__ tt) {
    int tid = blockIdx.x * 256 + threadIdx.x;
    int nth = gridDim.x * 256;
    for (int idx = tid; idx < W1N; idx += nth) {
        int j = idx & 7, lane = (idx >> 3) & 63, nf = (idx >> 9) & 3, ks = idx >> 11;
        int k = ks * 16 + ((lane >> 5) << 3) + j;
        int v = lane & 31;
        float val = 0.0f;
        if (v < VDIM) val = (nf < 3) ? gk[k * 84 + nf * 28 + v] : co[k * VDIM + v];
        unsigned short hi = f2bf_rne(val);
        float fh = __uint_as_float(((unsigned)hi) << 16);
        w1h[idx] = hi;
        w1l[idx] = f2bf_rne(val - fh);
    }
    for (int idx = tid; idx < W2N; idx += nth) {
        int j = idx & 7, lane = (idx >> 3) & 63, nf = (idx >> 9) & 3, ks = idx >> 11;
        int k = ks * 16 + ((lane >> 5) << 3) + j;
        int v = lane & 31;
        float val = 0.0f;
        if (v < VDIM && k < VDIM) val = (nf < 3) ? rk[k * 84 + nf * 28 + v] : uo[k * VDIM + v];
        unsigned short hi = f2bf_rne(val);
        float fh = __uint_as_float(((unsigned)hi) << 16);
        w2h[idx] = hi;
        w2l[idx] = f2bf_rne(val - fh);
    }
    if (tid < VDIM) {
        float s = 0.0f;
        for (int e = 0; e < VDIM; e++) s = fmaf(emb[tid * VDIM + e], wo[e], s);
        tt[tid] = s;
    }
}

#define MFMA(A, B, C) __builtin_amdgcn_mfma_f32_32x32x16_bf16(A, B, C, 0, 0, 0)
#define SPLIT8(A0, A1, AH, AL)                                        \
    {                                                                 \
        uint4 hu_, lu_;                                               \
        split2(A0.x, A0.y, hu_.x, lu_.x);                             \
        split2(A0.z, A0.w, hu_.y, lu_.y);                             \
        split2(A1.x, A1.y, hu_.z, lu_.z);                             \
        split2(A1.z, A1.w, hu_.w, lu_.w);                             \
        AH = __builtin_bit_cast(short8, hu_);                         \
        AL = __builtin_bit_cast(short8, lu_);                         \
    }
#define MFMA4(ACC, AH, AL, BH, BL)                                    \
    ACC = MFMA(AH, BH, ACC); ACC = MFMA(AL, BH, ACC);                 \
    ACC = MFMA(AH, BL, ACC); ACC = MFMA(AL, BL, ACC);

// async global->LDS, 16B per lane, linear dest
#define GLD_LDS16(G, L) __builtin_amdgcn_global_load_lds(                         \
    (const __attribute__((address_space(1))) void*)(G),                           \
    (__attribute__((address_space(3))) void*)(L), 16, 0, 0)

// ---- Main: K-split-2 x 2 M-frags (4 waves), B staged via global_load_lds,
//      A 1-deep register prefetch, LDS phased reduce, register epilogue ----
__global__ __launch_bounds__(256, 3) void gru_main_kernel(
    const float* __restrict__ x,    // [B,512]
    const int*   __restrict__ pp,   // [B,28]
    const float* __restrict__ ps,   // [B,28]
    const float* __restrict__ bias, // [2,84]
    const float* __restrict__ bo,   // [1,28]
    const unsigned short* __restrict__ w1h, const unsigned short* __restrict__ w1l,
    const unsigned short* __restrict__ w2h, const unsigned short* __restrict__ w2l,
    const float* __restrict__ tt,   // [28]
    float* __restrict__ out)
{
    // [stream(wid_k)][dbuf][hi/lo][frag(nf*64+lane)] : 32 KB
    __shared__ short8 bb[2][2][2][256];

    const int t = threadIdx.x;
    const int wid = t >> 6, l = t & 63;
    const int wid_m = wid & 1, wid_k = wid >> 1;
    const int cl = l & 31, gh = l >> 5;
    const long row0 = (long)blockIdx.x * TILE_R;
    const int m0x = 32 * wid_m;

    // ---- stage k-step 0 of both K-streams into dbuf0 (async) ----
    #pragma unroll
    for (int rr = 0; rr < 4; ++rr) {
        const int s = rr >> 1, p = rr & 1;
        const unsigned short* srcb = p ? w1l : w1h;
        GLD_LDS16(srcb + (s * 16) * 2048 + t * 8, &bb[s][0][p][t]);
    }

    // per-lane column scalars (v = cl)
    const int vc = (cl < VDIM) ? cl : (VDIM - 1);
    const float b0z = bias[vc],      b0r = bias[28 + vc],  b0h = bias[56 + vc];
    const float b1z = bias[84 + vc], b1r = bias[112 + vc], b1h = bias[140 + vc];
    const float bov = bo[vc];

    f32x16 accz = {}, accr = {}, acch = {}, accc = {}, hacch = {};

    // ---- A prefetch for x k-step 0 of this wave's K-half ----
    const float* xrow = x + (row0 + m0x + cl) * (long)FDIM + gh * 8;
    const int ks0 = wid_k * 16;
    float4 a0n = *(const float4*)(xrow + ks0 * 16);
    float4 a1n = *(const float4*)(xrow + ks0 * 16 + 4);

    // ---- h-GEMM: wave wid_k does h k-step wid_k (K=28 padded to 32) ----
    {
        const float* hrow = ps + (row0 + m0x + cl) * (long)VDIM;
        const short8* bh8 = (const short8*)w2h + l;
        const short8* bl8 = (const short8*)w2l + l;
        float4 a0, a1;
        if (wid_k == 0) {
            a0 = *(const float4*)(hrow + gh * 8);
            a1 = *(const float4*)(hrow + gh * 8 + 4);
        } else {
            a0 = *(const float4*)(hrow + 16 + gh * 8);   // k 16..19 | 24..27
            a1 = make_float4(0.f, 0.f, 0.f, 0.f);        // k 28..31 -> 0
            if (!gh) a1 = *(const float4*)(hrow + 20);   // k 20..23
        }
        short8 ah, al, bh, bl;
        SPLIT8(a0, a1, ah, al);
        const int ko = wid_k * 256;
        bh = bh8[ko];       bl = bl8[ko];       MFMA4(accz,  ah, al, bh, bl);
        bh = bh8[ko + 64];  bl = bl8[ko + 64];  MFMA4(accr,  ah, al, bh, bl);
        bh = bh8[ko + 128]; bl = bl8[ko + 128]; MFMA4(hacch, ah, al, bh, bl);
        bh = bh8[ko + 192]; bl = bl8[ko + 192]; MFMA4(accc,  ah, al, bh, bl);
    }

    __syncthreads();   // dbuf0 staged (vmcnt drained before barrier)

    // ---- x-GEMM: 16 k-steps per wave; stage next, compute current ----
    #pragma unroll
    for (int i = 0; i < 16; ++i) {
        float4 a0c = a0n, a1c = a1n;
        if (i + 1 < 16) {
            a0n = *(const float4*)(xrow + (ks0 + i + 1) * 16);
            a1n = *(const float4*)(xrow + (ks0 + i + 1) * 16 + 4);
            #pragma unroll
            for (int rr = 0; rr < 4; ++rr) {
                const int s = rr >> 1, p = rr & 1;
                const unsigned short* srcb = p ? w1l : w1h;
                GLD_LDS16(srcb + (s * 16 + i + 1) * 2048 + t * 8,
                          &bb[s][(i + 1) & 1][p][t]);
            }
        }
        short8 ah, al;
        SPLIT8(a0c, a1c, ah, al);
        const short8* Bh = &bb[wid_k][i & 1][0][0];
        const short8* Bl = &bb[wid_k][i & 1][1][0];
        short8 bh, bl;
        bh = Bh[l];        bl = Bl[l];        MFMA4(accz, ah, al, bh, bl);
        bh = Bh[64 + l];   bl = Bl[64 + l];   MFMA4(accr, ah, al, bh, bl);
        bh = Bh[128 + l];  bl = Bl[128 + l];  MFMA4(acch, ah, al, bh, bl);
        bh = Bh[192 + l];  bl = Bl[192 + l];  MFMA4(accc, ah, al, bh, bl);
        __syncthreads();
    }

    // ---- phased reduce: wid_k=1 partials -> wid_k=0 (8 KB alias on bb) ----
    float* rbuf = (float*)&bb[0][0][0][0];
#define REDUCE(ACC)                                                              \
    if (wid_k == 1) {                                                            \
        _Pragma("unroll")                                                        \
        for (int r = 0; r < 16; ++r) rbuf[(wid_m * 16 + r) * 64 + l] = ACC[r];   \
    }                                                                            \
    __syncthreads();                                                             \
    if (wid_k == 0) {                                                            \
        _Pragma("unroll")                                                        \
        for (int r = 0; r < 16; ++r) ACC[r] += rbuf[(wid_m * 16 + r) * 64 + l];  \
    }                                                                            \
    __syncthreads();

    REDUCE(accz)
    REDUCE(accr)
    REDUCE(acch)
    REDUCE(hacch)
    REDUCE(accc)
#undef REDUCE

    // ---- register epilogue on wid_k=0 waves (rows m0x..m0x+31) ----
    if (wid_k == 0) {
        #pragma unroll
        for (int r = 0; r < 16; ++r) {
            const int rowf = (r & 3) + ((r >> 2) << 3) + (gh << 2);
            const long orow = row0 + m0x + rowf;
            const float hp  = ps[orow * VDIM + vc];
            const int   ppv = pp[orow * VDIM + vc];
            const float ttv = tt[ppv];

            const float z  = sigmoidf_(accz[r] + b0z + b1z);
            const float rg = sigmoidf_(accr[r] + b0r + b1r);
            const float hc = tanhf_(acch[r] + b0h + rg * (hacch[r] + b1h));
            const float go = z * hp + (1.0f - z) * hc;
            const float logit = ttv + accc[r] + bov;

            float mx = (cl < VDIM) ? logit : -1e30f;
            mx = fmaxf(mx, __shfl_xor(mx, 16));
            mx = fmaxf(mx, __shfl_xor(mx, 8));
            mx = fmaxf(mx, __shfl_xor(mx, 4));
            mx = fmaxf(mx, __shfl_xor(mx, 2));
            mx = fmaxf(mx, __shfl_xor(mx, 1));
            float p = (cl < VDIM) ? __expf(logit - mx) : 0.0f;
            float s = p;
            s += __shfl_xor(s, 16);
            s += __shfl_xor(s, 8);
            s += __shfl_xor(s, 4);
            s += __shfl_xor(s, 2);
            s += __shfl_xor(s, 1);

            if (cl < VDIM) {
                out[orow * VDIM + cl] = p / s;
                out[(long)BATCH * VDIM + orow * VDIM + cl] = go;
            }
        }
    }
}

extern "C" void kernel_launch(void* const* d_in, const int* in_sizes, int n_in,
                              void* d_out, int out_size, void* d_ws, size_t ws_size,
                              hipStream_t stream) {
    const float* x    = (const float*)d_in[0];
    const int*   pp   = (const int*)  d_in[1];
    const float* ps   = (const float*)d_in[2];
    const float* gk   = (const float*)d_in[3];
    const float* rk   = (const float*)d_in[4];
    const float* bias = (const float*)d_in[5];
    const float* wo   = (const float*)d_in[6];
    const float* uo   = (const float*)d_in[7];
    const float* co   = (const float*)d_in[8];
    const float* bo   = (const float*)d_in[9];
    const float* emb  = (const float*)d_in[10];

    unsigned short* w1h = (unsigned short*)d_ws;   // 128 KB
    unsigned short* w1l = w1h + W1N;               // 128 KB
    unsigned short* w2h = w1l + W1N;               // 8 KB
    unsigned short* w2l = w2h + W2N;               // 8 KB
    float*          tt  = (float*)(w2l + W2N);     // 112 B

    prep_kernel<<<256, 256, 0, stream>>>(gk, co, rk, uo, emb, wo, w1h, w1l, w2h, w2l, tt);
    gru_main_kernel<<<BATCH / TILE_R, 256, 0, stream>>>(
        x, pp, ps, bias, bo, w1h, w1l, w2h, w2l, tt, (float*)d_out);
}